// Round 15
// baseline (188.537 us; speedup 1.0000x reference)
//
#include <hip/hip_runtime.h>
#include <cmath>

typedef __attribute__((ext_vector_type(4))) float f32x4;
typedef __attribute__((ext_vector_type(16))) float f32x16;
typedef __attribute__((ext_vector_type(8))) __bf16 bf16x8;
typedef __attribute__((ext_vector_type(8))) short s16x8;
typedef __attribute__((ext_vector_type(2))) unsigned int u32x2;

#define CB 4
#define CT 2048
#define CD 1024
#define CH 16
#define CDK 64
#define CBT 8192   // B*T
#define CBH 64     // B*H

#define GLOAD_LDS16(g, l)                                              \
  __builtin_amdgcn_global_load_lds(                                    \
      (const __attribute__((address_space(1))) unsigned int*)(g),      \
      (__attribute__((address_space(3))) unsigned int*)(l), 16, 0, 0)

__device__ __forceinline__ unsigned short f2bf(float f) {
  union { float f; unsigned u; } x; x.f = f;
  unsigned r = x.u + 0x7fffu + ((x.u >> 16) & 1u);
  return (unsigned short)(r >> 16);
}
__device__ __forceinline__ float bf2f(unsigned short b) {
  union { unsigned u; float f; } x; x.u = ((unsigned)b) << 16;
  return x.f;
}
__device__ __forceinline__ f32x4 mfma16(bf16x8 a, bf16x8 b, f32x4 c) {
  return __builtin_amdgcn_mfma_f32_16x16x32_bf16(a, b, c, 0, 0, 0);
}
__device__ __forceinline__ f32x16 mfma32(bf16x8 a, bf16x8 b, f32x16 c) {
  return __builtin_amdgcn_mfma_f32_32x32x16_bf16(a, b, c, 0, 0, 0);
}
__device__ __forceinline__ unsigned cvtpk(float lo, float hi) {
  unsigned r;
  asm("v_cvt_pk_bf16_f32 %0, %1, %2" : "=v"(r) : "v"(lo), "v"(hi));
  return r;
}

// ---------------- convert f32 -> bf16 (vectorized) ----------------
__global__ void convert_f32_bf16(const float* __restrict__ src,
                                 unsigned short* __restrict__ dst, int n) {
  int i = (blockIdx.x * blockDim.x + threadIdx.x) * 4;
  if (i >= n) return;
  float4 v = *(const float4*)(src + i);
  ushort4 o;
  o.x = f2bf(v.x); o.y = f2bf(v.y); o.z = f2bf(v.z); o.w = f2bf(v.w);
  *(ushort4*)(dst + i) = o;
}

// ---------------- transpose+convert: src f32 [R][C] -> dst bf16 [C][R] ----------------
__global__ void transpose_f32_bf16(const float* __restrict__ src,
                                   unsigned short* __restrict__ dst,
                                   int R, int C) {
  __shared__ float tile[32][33];
  const int x = threadIdx.x, y0 = threadIdx.y;       // block (32, 8)
  const int ct = blockIdx.x, rt = blockIdx.y;
#pragma unroll
  for (int k = 0; k < 4; ++k) {
    int r = rt * 32 + y0 + k * 8;
    tile[y0 + k * 8][x] = src[(size_t)r * C + ct * 32 + x];
  }
  __syncthreads();
#pragma unroll
  for (int k = 0; k < 4; ++k) {
    int c = ct * 32 + y0 + k * 8;
    dst[(size_t)c * R + rt * 32 + x] = f2bf(tile[x][y0 + k * 8]);
  }
}

// ---------------- 128^2-tile GEMM (m97 structure) — used for out-proj ----------------
// MODE 1: write fp32 to fout [M][N]
template <int MODE>
__global__ __launch_bounds__(256, 4) void gemm_bt(
    const unsigned short* __restrict__ A, const unsigned short* __restrict__ Bt,
    const float* __restrict__ bias, unsigned short* __restrict__ o0,
    unsigned short* __restrict__ o1, unsigned short* __restrict__ o2,
    float* __restrict__ fout, const float* __restrict__ cosT,
    const float* __restrict__ sinT, int M, int N, int K) {
  __shared__ __align__(16) unsigned short As[128 * 64];
  __shared__ __align__(16) unsigned short Bs[128 * 64];
  const int tid = threadIdx.x;
  const int lane = tid & 63, wid = tid >> 6;
  const int wr = wid >> 1, wc = wid & 1;
  const int m0 = blockIdx.x * 128, n0 = blockIdx.y * 128;
  const int l15 = lane & 15, l4 = lane >> 4;
  const int rx = l15 & 7;

  f32x4 acc[4][4];
#pragma unroll
  for (int i = 0; i < 4; ++i)
#pragma unroll
    for (int j = 0; j < 4; ++j) acc[i][j] = (f32x4){0.f, 0.f, 0.f, 0.f};

  const int srow = tid >> 3;
  const int scol = ((tid & 7) ^ (srow & 7)) * 8;
  const unsigned short* ag = A + (size_t)(m0 + srow) * K + scol;
  const unsigned short* bg = Bt + (size_t)(n0 + srow) * K + scol;
  unsigned short* asd = As + wid * 512;
  unsigned short* bsd = Bs + wid * 512;

  for (int k0 = 0; k0 < K; k0 += 64) {
#pragma unroll
    for (int p = 0; p < 4; ++p) {
      GLOAD_LDS16(ag + (size_t)(p * 32) * K + k0, asd + p * 2048);
      GLOAD_LDS16(bg + (size_t)(p * 32) * K + k0, bsd + p * 2048);
    }
    __syncthreads();
#pragma unroll
    for (int kk = 0; kk < 2; ++kk) {
      const int gsw = ((kk * 4 + l4) ^ rx) * 8;
      bf16x8 af[4], bfr[4];
#pragma unroll
      for (int i = 0; i < 4; ++i)
        af[i] = *(const bf16x8*)(&As[(wr * 64 + i * 16 + l15) * 64 + gsw]);
#pragma unroll
      for (int j = 0; j < 4; ++j)
        bfr[j] = *(const bf16x8*)(&Bs[(wc * 64 + j * 16 + l15) * 64 + gsw]);
#pragma unroll
      for (int i = 0; i < 4; ++i)
#pragma unroll
        for (int j = 0; j < 4; ++j)
          acc[i][j] = mfma16(af[i], bfr[j], acc[i][j]);
    }
    __syncthreads();
  }

  if (MODE == 1) {
#pragma unroll
    for (int i = 0; i < 4; ++i)
#pragma unroll
      for (int j = 0; j < 4; ++j) {
        const int row0 = m0 + wr * 64 + i * 16 + l4 * 4;
        const int col = n0 + wc * 64 + j * 16 + l15;
        const float bv = bias[col];
#pragma unroll
        for (int r = 0; r < 4; ++r)
          fout[(size_t)(row0 + r) * N + col] = acc[i][j][r] + bv;
      }
  }
}

// ---------------- 256^2-tile 8-phase GEMM with fused-RoPE scatter (QKV) ----------
// T2+T3+T4+T5: double-buffered 64KB tiles, half-tile stage events (1/phase),
// counted vmcnt(4) once per K-tile, per-phase barrier, setprio on MFMA.
// Stage event e: tile t=e>>2, part e&3 in {A-rows0-127, A-rows128-255, B0, B1},
// issued at phase e-5; tile t computed at phases 4t..4t+3 (quadrants).
__global__ __launch_bounds__(512, 2) void gemm256_qkv(
    const unsigned short* __restrict__ A, const unsigned short* __restrict__ Bt,
    const float* __restrict__ bias, unsigned short* __restrict__ o0,
    unsigned short* __restrict__ o1, unsigned short* __restrict__ o2,
    const float* __restrict__ cosT, const float* __restrict__ sinT,
    int M, int N, int K) {
  __shared__ __align__(16) unsigned short LDS[65536];  // 128 KB: A[2][16K] B[2][16K] shorts
  const int tid = threadIdx.x, lane = tid & 63, w = tid >> 6;  // 8 waves
  const int wr = w >> 2, wc = w & 3;                           // 2 x 4
  const int m0 = blockIdx.x * 256, n0 = blockIdx.y * 256;
  const int l15 = lane & 15, l4 = lane >> 4;
  const int rx = l15 & 7;
  const int NT = K >> 6;  // 16

  // stage-source lane geometry (both-sides swizzle, rule #21):
  // lane l covers row-in-half = w*16 + q*8 + (l>>3), source granule (l&7)^(l>>3)
  const int srow8 = lane >> 3;
  const int sg = ((lane & 7) ^ srow8) * 8;

  f32x4 acc[8][4];
#pragma unroll
  for (int i = 0; i < 8; ++i)
#pragma unroll
    for (int j = 0; j < 4; ++j) acc[i][j] = (f32x4){0.f, 0.f, 0.f, 0.f};

  auto STAGE = [&](int e) {
    const int t = e >> 2, h = e & 3;
    const int buf = t & 1;
    const int half = h & 1;
    const unsigned short* mat = (h < 2) ? A : Bt;
    const int rbase = ((h < 2) ? m0 : n0) + half * 128 + w * 16 + srow8;
    unsigned short* dst = LDS + ((h < 2) ? 0 : 32768) + buf * 16384 +
                          half * 8192 + w * 1024;
    const int k0 = t * 64;
#pragma unroll
    for (int q = 0; q < 2; ++q)
      GLOAD_LDS16(mat + (size_t)(rbase + q * 8) * K + k0 + sg, dst + q * 512);
  };

  // prologue: events 0..4 (tile0 all parts + tile1 A-half0)
  for (int e = 0; e < 5; ++e) STAGE(e);

  bf16x8 afr[4][2], bfA[2][2], bfB[2][2];

  for (int u = 0; u < NT; ++u) {
    const unsigned short* Ab = LDS + (u & 1) * 16384;
    const unsigned short* Bb = LDS + 32768 + (u & 1) * 16384;
    const int e0 = 4 * u;
    // ---------------- P0: quadrant rt0-3 x ct0-1 ----------------
    if (e0 + 5 < 4 * NT) STAGE(e0 + 5);
    if (u == NT - 1) asm volatile("s_waitcnt vmcnt(0)" ::: "memory");
    else             asm volatile("s_waitcnt vmcnt(4)" ::: "memory");
    __builtin_amdgcn_s_barrier();
#pragma unroll
    for (int rt = 0; rt < 4; ++rt)
#pragma unroll
      for (int kk = 0; kk < 2; ++kk)
        afr[rt][kk] = *(const bf16x8*)(Ab + (wr * 128 + rt * 16 + l15) * 64 +
                                       (((kk * 4 + l4) ^ rx) * 8));
#pragma unroll
    for (int ct = 0; ct < 2; ++ct)
#pragma unroll
      for (int kk = 0; kk < 2; ++kk)
        bfA[ct][kk] = *(const bf16x8*)(Bb + (wc * 64 + ct * 16 + l15) * 64 +
                                       (((kk * 4 + l4) ^ rx) * 8));
    __builtin_amdgcn_s_setprio(1);
#pragma unroll
    for (int rt = 0; rt < 4; ++rt)
#pragma unroll
      for (int ct = 0; ct < 2; ++ct)
#pragma unroll
        for (int kk = 0; kk < 2; ++kk)
          acc[rt][ct] = mfma16(afr[rt][kk], bfA[ct][kk], acc[rt][ct]);
    __builtin_amdgcn_s_setprio(0);
    __builtin_amdgcn_s_barrier();
    // ---------------- P1: quadrant rt0-3 x ct2-3 ----------------
    if (e0 + 6 < 4 * NT) STAGE(e0 + 6);
#pragma unroll
    for (int ct = 0; ct < 2; ++ct)
#pragma unroll
      for (int kk = 0; kk < 2; ++kk)
        bfB[ct][kk] = *(const bf16x8*)(Bb + (wc * 64 + (ct + 2) * 16 + l15) * 64 +
                                       (((kk * 4 + l4) ^ rx) * 8));
    __builtin_amdgcn_s_setprio(1);
#pragma unroll
    for (int rt = 0; rt < 4; ++rt)
#pragma unroll
      for (int ct = 0; ct < 2; ++ct)
#pragma unroll
        for (int kk = 0; kk < 2; ++kk)
          acc[rt][ct + 2] = mfma16(afr[rt][kk], bfB[ct][kk], acc[rt][ct + 2]);
    __builtin_amdgcn_s_setprio(0);
    __builtin_amdgcn_s_barrier();
    // ---------------- P2: quadrant rt4-7 x ct0-1 ----------------
    if (e0 + 7 < 4 * NT) STAGE(e0 + 7);
#pragma unroll
    for (int rt = 0; rt < 4; ++rt)
#pragma unroll
      for (int kk = 0; kk < 2; ++kk)
        afr[rt][kk] = *(const bf16x8*)(Ab + (wr * 128 + (rt + 4) * 16 + l15) * 64 +
                                       (((kk * 4 + l4) ^ rx) * 8));
    __builtin_amdgcn_s_setprio(1);
#pragma unroll
    for (int rt = 0; rt < 4; ++rt)
#pragma unroll
      for (int ct = 0; ct < 2; ++ct)
#pragma unroll
        for (int kk = 0; kk < 2; ++kk)
          acc[rt + 4][ct] = mfma16(afr[rt][kk], bfA[ct][kk], acc[rt + 4][ct]);
    __builtin_amdgcn_s_setprio(0);
    __builtin_amdgcn_s_barrier();
    // ---------------- P3: quadrant rt4-7 x ct2-3 (regs only) ----------------
    if (e0 + 8 < 4 * NT) STAGE(e0 + 8);
    __builtin_amdgcn_s_setprio(1);
#pragma unroll
    for (int rt = 0; rt < 4; ++rt)
#pragma unroll
      for (int ct = 0; ct < 2; ++ct)
#pragma unroll
        for (int kk = 0; kk < 2; ++kk)
          acc[rt + 4][ct + 2] = mfma16(afr[rt][kk], bfB[ct][kk], acc[rt + 4][ct + 2]);
    __builtin_amdgcn_s_setprio(0);
    __builtin_amdgcn_s_barrier();
  }

  // ---- epilogue: fused RoPE scatter (q,k) / transposed V ----
#pragma unroll
  for (int rt = 0; rt < 8; ++rt)
#pragma unroll
    for (int ct = 0; ct < 4; ++ct) {
      const int col = n0 + wc * 64 + ct * 16 + l15;
      const float bv = bias[col];
      const int h = col / 192;
      const int c = col % 192;
      const int sel = c >> 6;
      const int d = c & 63;
      if (sel < 2) {
        const int p = d >> 1;
        const bool even = (d & 1) == 0;
        const float qsc = (sel == 0) ? 0.18033688011112042592f : 1.0f;
        unsigned short* dst = (sel == 0) ? o0 : o1;
        const int dout = even ? p : (p + 32);
#pragma unroll
        for (int r = 0; r < 4; ++r) {
          const int row = m0 + wr * 128 + rt * 16 + l4 * 4 + r;
          const int b = row >> 11, t = row & 2047;
          const float v = acc[rt][ct][r] + bv;
          const float vp = __shfl_xor(v, 1);
          const float cs = cosT[t * 32 + p];
          const float sn = sinT[t * 32 + p];
          const float ve = even ? v : vp;
          const float vo = even ? vp : v;
          const float res = (even ? (ve * cs - vo * sn)
                                  : (ve * sn + vo * cs)) * qsc;
          dst[((size_t)((b * CH + h) * CT + t)) * CDK + dout] = f2bf(res);
        }
      } else {
#pragma unroll
        for (int r = 0; r < 4; ++r) {
          const int row = m0 + wr * 128 + rt * 16 + l4 * 4 + r;
          const int b = row >> 11, t = row & 2047;
          o2[((size_t)((b * CH + h) * CDK + d)) * CT + t] =
              f2bf(acc[rt][ct][r] + bv);
        }
      }
    }
}

// ---------------- flash attention v5: 8-wave 256-row blocks ----------------
__global__ __launch_bounds__(512, 4) void attn_fwd5(
    const unsigned short* __restrict__ qg, const unsigned short* __restrict__ kg,
    const unsigned short* __restrict__ vtg, unsigned short* __restrict__ ctx) {
  __shared__ __align__(16) unsigned short smem[24576];  // 48KB
  unsigned short* Ks = smem;
  unsigned short* Vt = smem + 12288;
  const int tid = threadIdx.x, lane = tid & 63, w = tid >> 6;
  const int l31 = lane & 31, hi = lane >> 5;
  const int b1 = blockIdx.x;
  const int g8 = b1 & 7, idx8 = b1 >> 3;
  const int qb = 7 - (idx8 & 7);
  const int bh = g8 + 8 * (idx8 >> 3);
  const unsigned short* qp = qg + ((size_t)bh * CT + qb * 256) * CDK;
  const unsigned short* kp = kg + (size_t)bh * CT * CDK;
  const unsigned short* vp = vtg + (size_t)bh * CDK * CT;

  bf16x8 qf[4];
  {
    const unsigned short* qrow = qp + (size_t)(w * 32 + l31) * CDK + hi * 8;
#pragma unroll
    for (int ks = 0; ks < 4; ++ks) qf[ks] = *(const bf16x8*)(qrow + ks * 16);
  }
#pragma unroll
  for (int ks = 0; ks < 4; ++ks)
    asm volatile("" :: "v"(*(const f32x4*)&qf[ks]));

  const int lr = lane >> 3;
  const int srow = w * 8 + lr;
  const int gsw = ((lane & 7) ^ lr) * 8;
  const unsigned short* ksrc = kp + (size_t)srow * CDK + gsw;
  const unsigned short* vsrc = vp + (size_t)srow * CT + gsw;
  const int ldo = w * 512;

  const int NJ = 4 * qb + 4;
  const int njw = ((qb * 256 + w * 32 + 31) >> 6) + 1;
  const int qrow_g = qb * 256 + w * 32 + l31;

  auto STAGE = [&](int t, int buf) {
    GLOAD_LDS16(ksrc + (size_t)t * 64 * CDK, Ks + buf * 4096 + ldo);
    GLOAD_LDS16(vsrc + (size_t)t * 64, Vt + buf * 4096 + ldo);
  };

  f32x16 oacc[2];
#pragma unroll
  for (int nb = 0; nb < 2; ++nb)
#pragma unroll
    for (int r = 0; r < 16; ++r) oacc[nb][r] = 0.f;
  float lsum = 0.f;

  STAGE(0, 0);
  STAGE(1, 1);

  int b0 = 0;
  for (int j = 0; j < NJ; ++j) {
    int bp = b0 + 2; if (bp > 2) bp -= 3;
    if (j + 2 < NJ) STAGE(j + 2, bp);
    const int pend = NJ - 1 - j;
    if (pend >= 2)      asm volatile("s_waitcnt vmcnt(4)" ::: "memory");
    else if (pend == 1) asm volatile("s_waitcnt vmcnt(2)" ::: "memory");
    else                asm volatile("s_waitcnt vmcnt(0)" ::: "memory");
    __builtin_amdgcn_s_barrier();

    if (j < njw) {
      const unsigned short* KB = Ks + b0 * 4096;
      const unsigned short* VB = Vt + b0 * 4096;

      f32x16 pacc[2];
      __builtin_amdgcn_s_setprio(1);
#pragma unroll
      for (int kb = 0; kb < 2; ++kb) {
#pragma unroll
        for (int r = 0; r < 16; ++r) pacc[kb][r] = 0.f;
#pragma unroll
        for (int ks = 0; ks < 4; ++ks) {
          const int row = kb * 32 + l31;
          bf16x8 kf = *(const bf16x8*)(KB + row * 64 + (((ks * 2 + hi) ^ (row & 7)) * 8));
          pacc[kb] = mfma32(kf, qf[ks], pacc[kb]);
        }
      }
      __builtin_amdgcn_s_setprio(0);

      if (j == njw - 1) {
        const int key0 = j * 64;
#pragma unroll
        for (int kb = 0; kb < 2; ++kb)
#pragma unroll
          for (int r = 0; r < 16; ++r) {
            const int key = key0 + kb * 32 + (r & 3) + 8 * (r >> 2) + 4 * hi;
            if (key > qrow_g) pacc[kb][r] = -1e30f;
          }
      }

#pragma unroll
      for (int kb = 0; kb < 2; ++kb)
#pragma unroll
        for (int r = 0; r < 16; ++r)
          pacc[kb][r] = __builtin_amdgcn_exp2f(pacc[kb][r]);
      float rs;
      {
        float t[16];
#pragma unroll
        for (int r = 0; r < 16; ++r) t[r] = pacc[0][r] + pacc[1][r];
#pragma unroll
        for (int s = 8; s > 0; s >>= 1)
#pragma unroll
          for (int r = 0; r < s; ++r) t[r] += t[r + s];
        rs = t[0];
      }
      {
        unsigned ru = __float_as_uint(rs);
        u32x2 sw = __builtin_amdgcn_permlane32_swap(ru, ru, false, false);
        rs += __uint_as_float(hi ? sw[0] : sw[1]);
      }
      lsum += rs;

      bf16x8 pf[4];
#pragma unroll
      for (int kb = 0; kb < 2; ++kb)
#pragma unroll
        for (int half = 0; half < 2; ++half) {
          const int b0i = half * 8;
          unsigned c0 = cvtpk(pacc[kb][b0i + 0], pacc[kb][b0i + 1]);
          unsigned c1 = cvtpk(pacc[kb][b0i + 2], pacc[kb][b0i + 3]);
          unsigned c2 = cvtpk(pacc[kb][b0i + 4], pacc[kb][b0i + 5]);
          unsigned c3 = cvtpk(pacc[kb][b0i + 6], pacc[kb][b0i + 7]);
          u32x2 r02 = __builtin_amdgcn_permlane32_swap(c0, c2, false, false);
          u32x2 r13 = __builtin_amdgcn_permlane32_swap(c1, c3, false, false);
          union { unsigned u[4]; bf16x8 v; } fr;
          fr.u[0] = r02[0]; fr.u[1] = r13[0]; fr.u[2] = r02[1]; fr.u[3] = r13[1];
          pf[kb * 2 + half] = fr.v;
        }

      __builtin_amdgcn_s_setprio(1);
#pragma unroll
      for (int nb = 0; nb < 2; ++nb)
#pragma unroll
        for (int ks = 0; ks < 4; ++ks) {
          const int row = nb * 32 + l31;
          bf16x8 vf = *(const bf16x8*)(VB + row * 64 + (((ks * 2 + hi) ^ (row & 7)) * 8));
          oacc[nb] = mfma32(vf, pf[ks], oacc[nb]);
        }
      __builtin_amdgcn_s_setprio(0);
    }

    __builtin_amdgcn_s_barrier();
    b0 = (b0 == 2) ? 0 : b0 + 1;
  }

  __syncthreads();

  unsigned short* tr = smem + w * 2048;
  const float inv = 1.f / lsum;
#pragma unroll
  for (int nb = 0; nb < 2; ++nb)
#pragma unroll
    for (int rp = 0; rp < 8; ++rp) {
      const int r = rp * 2;
      unsigned pkd = cvtpk(oacc[nb][r] * inv, oacc[nb][r + 1] * inv);
      const int d = nb * 32 + (r & 3) + 8 * (r >> 2) + 4 * hi;
      const int g = (d >> 3) ^ (l31 & 7);
      *(unsigned*)(tr + l31 * 64 + g * 8 + (d & 7)) = pkd;
    }
  const int b = bh >> 4, h = bh & 15;
#pragma unroll
  for (int s = 0; s < 4; ++s) {
    const int c = s * 64 + lane;
    const int qr = c >> 3, g = c & 7;
    s16x8 row = *(const s16x8*)(tr + qr * 64 + ((g ^ (qr & 7))) * 8);
    const int tok = qb * 256 + w * 32 + qr;
    *(s16x8*)(ctx + ((size_t)(b * CT + tok)) * CD + h * CDK + g * 8) = row;
  }
}

extern "C" void kernel_launch(void* const* d_in, const int* in_sizes, int n_in,
                              void* d_out, int out_size, void* d_ws, size_t ws_size,
                              hipStream_t stream) {
  (void)in_sizes; (void)n_in; (void)out_size; (void)ws_size;
  const float* x     = (const float*)d_in[0];
  const float* W_qkv = (const float*)d_in[1];
  const float* b_qkv = (const float*)d_in[2];
  const float* W_out = (const float*)d_in[3];
  const float* b_out = (const float*)d_in[4];
  const float* cosT  = (const float*)d_in[5];
  const float* sinT  = (const float*)d_in[6];
  float* out = (float*)d_out;

  unsigned short* xb   = (unsigned short*)d_ws;            // [8192][1024]
  unsigned short* wqt  = xb + (size_t)CBT * CD;            // [3072][1024]
  unsigned short* wot  = wqt + (size_t)3 * CD * CD;        // [1024][1024]
  unsigned short* qbuf = wot + (size_t)CD * CD;            // [64][2048][64]
  unsigned short* kbuf = qbuf + (size_t)CBH * CT * CDK;    // [64][2048][64]
  unsigned short* vbuf = kbuf + (size_t)CBH * CT * CDK;    // [64][64][2048] (V^T)
  unsigned short* ctx  = vbuf + (size_t)CBH * CT * CDK;    // [8192][1024]

  {
    int n = CBT * CD;
    convert_f32_bf16<<<n / (256 * 4), 256, 0, stream>>>(x, xb, n);
  }
  transpose_f32_bf16<<<dim3(3 * CD / 32, CD / 32), dim3(32, 8), 0, stream>>>(
      W_qkv, wqt, CD, 3 * CD);
  transpose_f32_bf16<<<dim3(CD / 32, CD / 32), dim3(32, 8), 0, stream>>>(
      W_out, wot, CD, CD);
  // QKV GEMM: 256^2 8-phase with fused RoPE scatter
  gemm256_qkv<<<dim3(CBT / 256, 3 * CD / 256), 512, 0, stream>>>(
      xb, wqt, b_qkv, qbuf, kbuf, vbuf, cosT, sinT, CBT, 3 * CD, CD);
  attn_fwd5<<<dim3(512), 512, 0, stream>>>(qbuf, kbuf, vbuf, ctx);
  gemm_bt<1><<<dim3(CBT / 128, CD / 128), 256, 0, stream>>>(
      ctx, wot, b_out, nullptr, nullptr, nullptr, out, nullptr, nullptr,
      CBT, CD, CD);
}

// Round 16
// 166.521 us; speedup vs baseline: 1.1322x; 1.1322x over previous
//
#include <hip/hip_runtime.h>
#include <cmath>

typedef __attribute__((ext_vector_type(4))) float f32x4;
typedef __attribute__((ext_vector_type(16))) float f32x16;
typedef __attribute__((ext_vector_type(8))) __bf16 bf16x8;
typedef __attribute__((ext_vector_type(8))) short s16x8;
typedef __attribute__((ext_vector_type(2))) unsigned int u32x2;

#define CB 4
#define CT 2048
#define CD 1024
#define CH 16
#define CDK 64
#define CBT 8192   // B*T
#define CBH 64     // B*H

#define GLOAD_LDS16(g, l)                                              \
  __builtin_amdgcn_global_load_lds(                                    \
      (const __attribute__((address_space(1))) unsigned int*)(g),      \
      (__attribute__((address_space(3))) unsigned int*)(l), 16, 0, 0)

__device__ __forceinline__ unsigned short f2bf(float f) {
  union { float f; unsigned u; } x; x.f = f;
  unsigned r = x.u + 0x7fffu + ((x.u >> 16) & 1u);
  return (unsigned short)(r >> 16);
}
__device__ __forceinline__ float bf2f(unsigned short b) {
  union { unsigned u; float f; } x; x.u = ((unsigned)b) << 16;
  return x.f;
}
__device__ __forceinline__ f32x4 mfma16(bf16x8 a, bf16x8 b, f32x4 c) {
  return __builtin_amdgcn_mfma_f32_16x16x32_bf16(a, b, c, 0, 0, 0);
}
__device__ __forceinline__ f32x16 mfma32(bf16x8 a, bf16x8 b, f32x16 c) {
  return __builtin_amdgcn_mfma_f32_32x32x16_bf16(a, b, c, 0, 0, 0);
}
__device__ __forceinline__ unsigned cvtpk(float lo, float hi) {
  unsigned r;
  asm("v_cvt_pk_bf16_f32 %0, %1, %2" : "=v"(r) : "v"(lo), "v"(hi));
  return r;
}

// ---------------- convert f32 -> bf16 (vectorized) ----------------
__global__ void convert_f32_bf16(const float* __restrict__ src,
                                 unsigned short* __restrict__ dst, int n) {
  int i = (blockIdx.x * blockDim.x + threadIdx.x) * 4;
  if (i >= n) return;
  float4 v = *(const float4*)(src + i);
  ushort4 o;
  o.x = f2bf(v.x); o.y = f2bf(v.y); o.z = f2bf(v.z); o.w = f2bf(v.w);
  *(ushort4*)(dst + i) = o;
}

// ---------------- merged transpose+convert for both weights ----------------
// blockIdx.x < 96: W_qkv f32 [1024][3072] -> wqt bf16 [3072][1024]
// else:            W_out f32 [1024][1024] -> wot bf16 [1024][1024]
__global__ void transpose_weights(const float* __restrict__ wqkv,
                                  unsigned short* __restrict__ wqt,
                                  const float* __restrict__ wout,
                                  unsigned short* __restrict__ wot) {
  __shared__ float tile[32][33];
  const int x = threadIdx.x, y0 = threadIdx.y;  // block (32, 8)
  const int bx = blockIdx.x, rt = blockIdx.y;
  const float* src;
  unsigned short* dst;
  int C, ct;
  if (bx < 96) { src = wqkv; dst = wqt; C = 3072; ct = bx; }
  else         { src = wout; dst = wot; C = 1024; ct = bx - 96; }
  const int R = 1024;
#pragma unroll
  for (int k = 0; k < 4; ++k) {
    int r = rt * 32 + y0 + k * 8;
    tile[y0 + k * 8][x] = src[(size_t)r * C + ct * 32 + x];
  }
  __syncthreads();
#pragma unroll
  for (int k = 0; k < 4; ++k) {
    int c = ct * 32 + y0 + k * 8;
    dst[(size_t)c * R + rt * 32 + x] = f2bf(tile[x][y0 + k * 8]);
  }
}

// ---------------- GEMM: C = A(bf16 [M][K]) * Bt(bf16 [N][K])^T + bias ----------------
// Staging via global_load_lds width=16 (m97 structure). LDS linear [128][64]
// with T2 both-sides XOR swizzle (rule #21). launch_bounds(256,4).
// MODE 0: fused-RoPE scatter: q,k rotated in f32 (+softmax scale into q) and
//         scattered into [BH][T][DK]; v TRANSPOSED into [BH][DK][T]
// MODE 1: write fp32 to fout [M][N]
template <int MODE>
__global__ __launch_bounds__(256, 4) void gemm_bt(
    const unsigned short* __restrict__ A, const unsigned short* __restrict__ Bt,
    const float* __restrict__ bias, unsigned short* __restrict__ o0,
    unsigned short* __restrict__ o1, unsigned short* __restrict__ o2,
    float* __restrict__ fout, const float* __restrict__ cosT,
    const float* __restrict__ sinT, int M, int N, int K) {
  __shared__ __align__(16) unsigned short As[128 * 64];
  __shared__ __align__(16) unsigned short Bs[128 * 64];
  const int tid = threadIdx.x;
  const int lane = tid & 63, wid = tid >> 6;
  const int wr = wid >> 1, wc = wid & 1;
  const int m0 = blockIdx.x * 128, n0 = blockIdx.y * 128;
  const int l15 = lane & 15, l4 = lane >> 4;
  const int rx = l15 & 7;

  f32x4 acc[4][4];
#pragma unroll
  for (int i = 0; i < 4; ++i)
#pragma unroll
    for (int j = 0; j < 4; ++j) acc[i][j] = (f32x4){0.f, 0.f, 0.f, 0.f};

  const int srow = tid >> 3;
  const int scol = ((tid & 7) ^ (srow & 7)) * 8;
  const unsigned short* ag = A + (size_t)(m0 + srow) * K + scol;
  const unsigned short* bg = Bt + (size_t)(n0 + srow) * K + scol;
  unsigned short* asd = As + wid * 512;
  unsigned short* bsd = Bs + wid * 512;

  for (int k0 = 0; k0 < K; k0 += 64) {
#pragma unroll
    for (int p = 0; p < 4; ++p) {
      GLOAD_LDS16(ag + (size_t)(p * 32) * K + k0, asd + p * 2048);
      GLOAD_LDS16(bg + (size_t)(p * 32) * K + k0, bsd + p * 2048);
    }
    __syncthreads();
#pragma unroll
    for (int kk = 0; kk < 2; ++kk) {
      const int gsw = ((kk * 4 + l4) ^ rx) * 8;
      bf16x8 af[4], bfr[4];
#pragma unroll
      for (int i = 0; i < 4; ++i)
        af[i] = *(const bf16x8*)(&As[(wr * 64 + i * 16 + l15) * 64 + gsw]);
#pragma unroll
      for (int j = 0; j < 4; ++j)
        bfr[j] = *(const bf16x8*)(&Bs[(wc * 64 + j * 16 + l15) * 64 + gsw]);
#pragma unroll
      for (int i = 0; i < 4; ++i)
#pragma unroll
        for (int j = 0; j < 4; ++j)
          acc[i][j] = mfma16(af[i], bfr[j], acc[i][j]);
    }
    __syncthreads();
  }

  if (MODE == 1) {
#pragma unroll
    for (int i = 0; i < 4; ++i)
#pragma unroll
      for (int j = 0; j < 4; ++j) {
        const int row0 = m0 + wr * 64 + i * 16 + l4 * 4;
        const int col = n0 + wc * 64 + j * 16 + l15;
        const float bv = bias[col];
#pragma unroll
        for (int r = 0; r < 4; ++r)
          fout[(size_t)(row0 + r) * N + col] = acc[i][j][r] + bv;
      }
  } else {
#pragma unroll
    for (int i = 0; i < 4; ++i)
#pragma unroll
      for (int j = 0; j < 4; ++j) {
        const int col = n0 + wc * 64 + j * 16 + l15;
        const float bv = bias[col];
        const int h = col / 192;
        const int c = col % 192;
        const int sel = c >> 6;
        const int d = c & 63;
        if (sel < 2) {
          const int p = d >> 1;
          const bool even = (d & 1) == 0;
          const float qsc = (sel == 0) ? 0.18033688011112042592f : 1.0f;
          unsigned short* dst = (sel == 0) ? o0 : o1;
          const int dout = even ? p : (p + 32);
#pragma unroll
          for (int r = 0; r < 4; ++r) {
            const int row = m0 + wr * 64 + i * 16 + l4 * 4 + r;
            const int b = row >> 11, t = row & 2047;
            const float v = acc[i][j][r] + bv;
            const float vp = __shfl_xor(v, 1);
            const float cs = cosT[t * 32 + p];
            const float sn = sinT[t * 32 + p];
            const float ve = even ? v : vp;
            const float vo = even ? vp : v;
            const float res = (even ? (ve * cs - vo * sn)
                                    : (ve * sn + vo * cs)) * qsc;
            dst[((size_t)((b * CH + h) * CT + t)) * CDK + dout] = f2bf(res);
          }
        } else {
#pragma unroll
          for (int r = 0; r < 4; ++r) {
            const int row = m0 + wr * 64 + i * 16 + l4 * 4 + r;
            const int b = row >> 11, t = row & 2047;
            o2[((size_t)((b * CH + h) * CDK + d)) * CT + t] =
                f2bf(acc[i][j][r] + bv);
          }
        }
      }
  }
}

// ---------------- flash attention v5: 8-wave 256-row blocks ----------------
// Counted-vmcnt 3-buffer pipeline, XCD-local + LPT remap, max-free softmax,
// T12 P-frags, setprio.
__global__ __launch_bounds__(512, 4) void attn_fwd5(
    const unsigned short* __restrict__ qg, const unsigned short* __restrict__ kg,
    const unsigned short* __restrict__ vtg, unsigned short* __restrict__ ctx) {
  __shared__ __align__(16) unsigned short smem[24576];  // 48KB
  unsigned short* Ks = smem;
  unsigned short* Vt = smem + 12288;
  const int tid = threadIdx.x, lane = tid & 63, w = tid >> 6;
  const int l31 = lane & 31, hi = lane >> 5;
  const int b1 = blockIdx.x;
  const int g8 = b1 & 7, idx8 = b1 >> 3;
  const int qb = 7 - (idx8 & 7);
  const int bh = g8 + 8 * (idx8 >> 3);
  const unsigned short* qp = qg + ((size_t)bh * CT + qb * 256) * CDK;
  const unsigned short* kp = kg + (size_t)bh * CT * CDK;
  const unsigned short* vp = vtg + (size_t)bh * CDK * CT;

  bf16x8 qf[4];
  {
    const unsigned short* qrow = qp + (size_t)(w * 32 + l31) * CDK + hi * 8;
#pragma unroll
    for (int ks = 0; ks < 4; ++ks) qf[ks] = *(const bf16x8*)(qrow + ks * 16);
  }
#pragma unroll
  for (int ks = 0; ks < 4; ++ks)
    asm volatile("" :: "v"(*(const f32x4*)&qf[ks]));

  const int lr = lane >> 3;
  const int srow = w * 8 + lr;
  const int gsw = ((lane & 7) ^ lr) * 8;
  const unsigned short* ksrc = kp + (size_t)srow * CDK + gsw;
  const unsigned short* vsrc = vp + (size_t)srow * CT + gsw;
  const int ldo = w * 512;

  const int NJ = 4 * qb + 4;
  const int njw = ((qb * 256 + w * 32 + 31) >> 6) + 1;
  const int qrow_g = qb * 256 + w * 32 + l31;

  auto STAGE = [&](int t, int buf) {
    GLOAD_LDS16(ksrc + (size_t)t * 64 * CDK, Ks + buf * 4096 + ldo);
    GLOAD_LDS16(vsrc + (size_t)t * 64, Vt + buf * 4096 + ldo);
  };

  f32x16 oacc[2];
#pragma unroll
  for (int nb = 0; nb < 2; ++nb)
#pragma unroll
    for (int r = 0; r < 16; ++r) oacc[nb][r] = 0.f;
  float lsum = 0.f;

  STAGE(0, 0);
  STAGE(1, 1);

  int b0 = 0;
  for (int j = 0; j < NJ; ++j) {
    int bp = b0 + 2; if (bp > 2) bp -= 3;
    if (j + 2 < NJ) STAGE(j + 2, bp);
    const int pend = NJ - 1 - j;
    if (pend >= 2)      asm volatile("s_waitcnt vmcnt(4)" ::: "memory");
    else if (pend == 1) asm volatile("s_waitcnt vmcnt(2)" ::: "memory");
    else                asm volatile("s_waitcnt vmcnt(0)" ::: "memory");
    __builtin_amdgcn_s_barrier();

    if (j < njw) {
      const unsigned short* KB = Ks + b0 * 4096;
      const unsigned short* VB = Vt + b0 * 4096;

      f32x16 pacc[2];
      __builtin_amdgcn_s_setprio(1);
#pragma unroll
      for (int kb = 0; kb < 2; ++kb) {
#pragma unroll
        for (int r = 0; r < 16; ++r) pacc[kb][r] = 0.f;
#pragma unroll
        for (int ks = 0; ks < 4; ++ks) {
          const int row = kb * 32 + l31;
          bf16x8 kf = *(const bf16x8*)(KB + row * 64 + (((ks * 2 + hi) ^ (row & 7)) * 8));
          pacc[kb] = mfma32(kf, qf[ks], pacc[kb]);
        }
      }
      __builtin_amdgcn_s_setprio(0);

      if (j == njw - 1) {
        const int key0 = j * 64;
#pragma unroll
        for (int kb = 0; kb < 2; ++kb)
#pragma unroll
          for (int r = 0; r < 16; ++r) {
            const int key = key0 + kb * 32 + (r & 3) + 8 * (r >> 2) + 4 * hi;
            if (key > qrow_g) pacc[kb][r] = -1e30f;
          }
      }

#pragma unroll
      for (int kb = 0; kb < 2; ++kb)
#pragma unroll
        for (int r = 0; r < 16; ++r)
          pacc[kb][r] = __builtin_amdgcn_exp2f(pacc[kb][r]);
      float rs;
      {
        float t[16];
#pragma unroll
        for (int r = 0; r < 16; ++r) t[r] = pacc[0][r] + pacc[1][r];
#pragma unroll
        for (int s = 8; s > 0; s >>= 1)
#pragma unroll
          for (int r = 0; r < s; ++r) t[r] += t[r + s];
        rs = t[0];
      }
      {
        unsigned ru = __float_as_uint(rs);
        u32x2 sw = __builtin_amdgcn_permlane32_swap(ru, ru, false, false);
        rs += __uint_as_float(hi ? sw[0] : sw[1]);
      }
      lsum += rs;

      bf16x8 pf[4];
#pragma unroll
      for (int kb = 0; kb < 2; ++kb)
#pragma unroll
        for (int half = 0; half < 2; ++half) {
          const int b0i = half * 8;
          unsigned c0 = cvtpk(pacc[kb][b0i + 0], pacc[kb][b0i + 1]);
          unsigned c1 = cvtpk(pacc[kb][b0i + 2], pacc[kb][b0i + 3]);
          unsigned c2 = cvtpk(pacc[kb][b0i + 4], pacc[kb][b0i + 5]);
          unsigned c3 = cvtpk(pacc[kb][b0i + 6], pacc[kb][b0i + 7]);
          u32x2 r02 = __builtin_amdgcn_permlane32_swap(c0, c2, false, false);
          u32x2 r13 = __builtin_amdgcn_permlane32_swap(c1, c3, false, false);
          union { unsigned u[4]; bf16x8 v; } fr;
          fr.u[0] = r02[0]; fr.u[1] = r13[0]; fr.u[2] = r02[1]; fr.u[3] = r13[1];
          pf[kb * 2 + half] = fr.v;
        }

      __builtin_amdgcn_s_setprio(1);
#pragma unroll
      for (int nb = 0; nb < 2; ++nb)
#pragma unroll
        for (int ks = 0; ks < 4; ++ks) {
          const int row = nb * 32 + l31;
          bf16x8 vf = *(const bf16x8*)(VB + row * 64 + (((ks * 2 + hi) ^ (row & 7)) * 8));
          oacc[nb] = mfma32(vf, pf[ks], oacc[nb]);
        }
      __builtin_amdgcn_s_setprio(0);
    }

    __builtin_amdgcn_s_barrier();
    b0 = (b0 == 2) ? 0 : b0 + 1;
  }

  __syncthreads();

  unsigned short* tr = smem + w * 2048;
  const float inv = 1.f / lsum;
#pragma unroll
  for (int nb = 0; nb < 2; ++nb)
#pragma unroll
    for (int rp = 0; rp < 8; ++rp) {
      const int r = rp * 2;
      unsigned pkd = cvtpk(oacc[nb][r] * inv, oacc[nb][r + 1] * inv);
      const int d = nb * 32 + (r & 3) + 8 * (r >> 2) + 4 * hi;
      const int g = (d >> 3) ^ (l31 & 7);
      *(unsigned*)(tr + l31 * 64 + g * 8 + (d & 7)) = pkd;
    }
  const int b = bh >> 4, h = bh & 15;
#pragma unroll
  for (int s = 0; s < 4; ++s) {
    const int c = s * 64 + lane;
    const int qr = c >> 3, g = c & 7;
    s16x8 row = *(const s16x8*)(tr + qr * 64 + ((g ^ (qr & 7))) * 8);
    const int tok = qb * 256 + w * 32 + qr;
    *(s16x8*)(ctx + ((size_t)(b * CT + tok)) * CD + h * CDK + g * 8) = row;
  }
}

extern "C" void kernel_launch(void* const* d_in, const int* in_sizes, int n_in,
                              void* d_out, int out_size, void* d_ws, size_t ws_size,
                              hipStream_t stream) {
  (void)in_sizes; (void)n_in; (void)out_size; (void)ws_size;
  const float* x     = (const float*)d_in[0];
  const float* W_qkv = (const float*)d_in[1];
  const float* b_qkv = (const float*)d_in[2];
  const float* W_out = (const float*)d_in[3];
  const float* b_out = (const float*)d_in[4];
  const float* cosT  = (const float*)d_in[5];
  const float* sinT  = (const float*)d_in[6];
  float* out = (float*)d_out;

  unsigned short* xb   = (unsigned short*)d_ws;            // [8192][1024]
  unsigned short* wqt  = xb + (size_t)CBT * CD;            // [3072][1024]
  unsigned short* wot  = wqt + (size_t)3 * CD * CD;        // [1024][1024]
  unsigned short* qbuf = wot + (size_t)CD * CD;            // [64][2048][64]
  unsigned short* kbuf = qbuf + (size_t)CBH * CT * CDK;    // [64][2048][64]
  unsigned short* vbuf = kbuf + (size_t)CBH * CT * CDK;    // [64][64][2048] (V^T)
  unsigned short* ctx  = vbuf + (size_t)CBH * CT * CDK;    // [8192][1024]

  {
    int n = CBT * CD;
    convert_f32_bf16<<<n / (256 * 4), 256, 0, stream>>>(x, xb, n);
  }
  transpose_weights<<<dim3(128, 32), dim3(32, 8), 0, stream>>>(
      W_qkv, wqt, W_out, wot);
  // QKV GEMM with fused RoPE epilogue (known-good R14 config)
  gemm_bt<0><<<dim3(CBT / 128, 3 * CD / 128), 256, 0, stream>>>(
      xb, wqt, b_qkv, qbuf, kbuf, vbuf, nullptr, cosT, sinT, CBT, 3 * CD, CD);
  attn_fwd5<<<dim3(512), 512, 0, stream>>>(qbuf, kbuf, vbuf, ctx);
  gemm_bt<1><<<dim3(CBT / 128, CD / 128), 256, 0, stream>>>(
      ctx, wot, b_out, nullptr, nullptr, nullptr, out, nullptr, nullptr,
      CBT, CD, CD);
}

// Round 17
// 161.382 us; speedup vs baseline: 1.1683x; 1.0318x over previous
//
#include <hip/hip_runtime.h>
#include <cmath>

typedef __attribute__((ext_vector_type(4))) float f32x4;
typedef __attribute__((ext_vector_type(16))) float f32x16;
typedef __attribute__((ext_vector_type(8))) __bf16 bf16x8;
typedef __attribute__((ext_vector_type(8))) short s16x8;
typedef __attribute__((ext_vector_type(2))) unsigned int u32x2;

#define CB 4
#define CT 2048
#define CD 1024
#define CH 16
#define CDK 64
#define CBT 8192   // B*T
#define CBH 64     // B*H

#define GLOAD_LDS16(g, l)                                              \
  __builtin_amdgcn_global_load_lds(                                    \
      (const __attribute__((address_space(1))) unsigned int*)(g),      \
      (__attribute__((address_space(3))) unsigned int*)(l), 16, 0, 0)

__device__ __forceinline__ unsigned short f2bf(float f) {
  union { float f; unsigned u; } x; x.f = f;
  unsigned r = x.u + 0x7fffu + ((x.u >> 16) & 1u);
  return (unsigned short)(r >> 16);
}
__device__ __forceinline__ float bf2f(unsigned short b) {
  union { unsigned u; float f; } x; x.u = ((unsigned)b) << 16;
  return x.f;
}
__device__ __forceinline__ f32x4 mfma16(bf16x8 a, bf16x8 b, f32x4 c) {
  return __builtin_amdgcn_mfma_f32_16x16x32_bf16(a, b, c, 0, 0, 0);
}
__device__ __forceinline__ f32x16 mfma32(bf16x8 a, bf16x8 b, f32x16 c) {
  return __builtin_amdgcn_mfma_f32_32x32x16_bf16(a, b, c, 0, 0, 0);
}
__device__ __forceinline__ unsigned cvtpk(float lo, float hi) {
  unsigned r;
  asm("v_cvt_pk_bf16_f32 %0, %1, %2" : "=v"(r) : "v"(lo), "v"(hi));
  return r;
}

// ---------------- merged prep: convert x (blocks 0..8191) + transpose weights ----------------
// blocks 8192..12287: bt=b-8192; bx=bt&127 (<96: W_qkv col-tile, else W_out),
// rt=bt>>7. Same math as the previous split kernels.
__global__ void prep_inputs(const float* __restrict__ x,
                            unsigned short* __restrict__ xb,
                            const float* __restrict__ wqkv,
                            unsigned short* __restrict__ wqt,
                            const float* __restrict__ wout,
                            unsigned short* __restrict__ wot) {
  __shared__ float tile[32][33];
  const int b = blockIdx.x, tid = threadIdx.x;
  if (b < 8192) {
    const int i = (b * 256 + tid) * 4;
    float4 v = *(const float4*)(x + i);
    ushort4 o;
    o.x = f2bf(v.x); o.y = f2bf(v.y); o.z = f2bf(v.z); o.w = f2bf(v.w);
    *(ushort4*)(xb + i) = o;
    return;
  }
  const int bt = b - 8192;
  const int bx = bt & 127, rt = bt >> 7;
  const int xx = tid & 31, y0 = tid >> 5;  // (32, 8)
  const float* src;
  unsigned short* dst;
  int C, ct;
  if (bx < 96) { src = wqkv; dst = wqt; C = 3072; ct = bx; }
  else         { src = wout; dst = wot; C = 1024; ct = bx - 96; }
  const int R = 1024;
#pragma unroll
  for (int k = 0; k < 4; ++k) {
    int r = rt * 32 + y0 + k * 8;
    tile[y0 + k * 8][xx] = src[(size_t)r * C + ct * 32 + xx];
  }
  __syncthreads();
#pragma unroll
  for (int k = 0; k < 4; ++k) {
    int c = ct * 32 + y0 + k * 8;
    dst[(size_t)c * R + rt * 32 + xx] = f2bf(tile[xx][y0 + k * 8]);
  }
}

// ---------------- GEMM: C = A(bf16 [M][K]) * Bt(bf16 [N][K])^T + bias ----------------
// Staging via global_load_lds width=16 (m97 structure), T2 both-sides XOR
// swizzle (rule #21), launch_bounds(256,4).
// MODE 0: INTERLEAVED-RoPE scatter: q'[2p]=x c - x' s, q'[2p+1]=x s + x' c at
//   position d itself (common d-permutation of q,k preserves scores; attn is
//   d-agnostic) -> lane-coalesced stores. V packed 8B stores into [BH][DK][T].
// MODE 1: write fp32 to fout [M][N]
template <int MODE>
__global__ __launch_bounds__(256, 4) void gemm_bt(
    const unsigned short* __restrict__ A, const unsigned short* __restrict__ Bt,
    const float* __restrict__ bias, unsigned short* __restrict__ o0,
    unsigned short* __restrict__ o1, unsigned short* __restrict__ o2,
    float* __restrict__ fout, const float* __restrict__ cosT,
    const float* __restrict__ sinT, int M, int N, int K) {
  __shared__ __align__(16) unsigned short As[128 * 64];
  __shared__ __align__(16) unsigned short Bs[128 * 64];
  const int tid = threadIdx.x;
  const int lane = tid & 63, wid = tid >> 6;
  const int wr = wid >> 1, wc = wid & 1;
  const int m0 = blockIdx.x * 128, n0 = blockIdx.y * 128;
  const int l15 = lane & 15, l4 = lane >> 4;
  const int rx = l15 & 7;

  f32x4 acc[4][4];
#pragma unroll
  for (int i = 0; i < 4; ++i)
#pragma unroll
    for (int j = 0; j < 4; ++j) acc[i][j] = (f32x4){0.f, 0.f, 0.f, 0.f};

  const int srow = tid >> 3;
  const int scol = ((tid & 7) ^ (srow & 7)) * 8;
  const unsigned short* ag = A + (size_t)(m0 + srow) * K + scol;
  const unsigned short* bg = Bt + (size_t)(n0 + srow) * K + scol;
  unsigned short* asd = As + wid * 512;
  unsigned short* bsd = Bs + wid * 512;

  for (int k0 = 0; k0 < K; k0 += 64) {
#pragma unroll
    for (int p = 0; p < 4; ++p) {
      GLOAD_LDS16(ag + (size_t)(p * 32) * K + k0, asd + p * 2048);
      GLOAD_LDS16(bg + (size_t)(p * 32) * K + k0, bsd + p * 2048);
    }
    __syncthreads();
#pragma unroll
    for (int kk = 0; kk < 2; ++kk) {
      const int gsw = ((kk * 4 + l4) ^ rx) * 8;
      bf16x8 af[4], bfr[4];
#pragma unroll
      for (int i = 0; i < 4; ++i)
        af[i] = *(const bf16x8*)(&As[(wr * 64 + i * 16 + l15) * 64 + gsw]);
#pragma unroll
      for (int j = 0; j < 4; ++j)
        bfr[j] = *(const bf16x8*)(&Bs[(wc * 64 + j * 16 + l15) * 64 + gsw]);
#pragma unroll
      for (int i = 0; i < 4; ++i)
#pragma unroll
        for (int j = 0; j < 4; ++j)
          acc[i][j] = mfma16(af[i], bfr[j], acc[i][j]);
    }
    __syncthreads();
  }

  if (MODE == 1) {
#pragma unroll
    for (int i = 0; i < 4; ++i)
#pragma unroll
      for (int j = 0; j < 4; ++j) {
        const int row0 = m0 + wr * 64 + i * 16 + l4 * 4;
        const int col = n0 + wc * 64 + j * 16 + l15;
        const float bv = bias[col];
#pragma unroll
        for (int r = 0; r < 4; ++r)
          fout[(size_t)(row0 + r) * N + col] = acc[i][j][r] + bv;
      }
  } else {
#pragma unroll
    for (int i = 0; i < 4; ++i)
#pragma unroll
      for (int j = 0; j < 4; ++j) {
        const int col = n0 + wc * 64 + j * 16 + l15;
        const float bv = bias[col];
        const int h = col / 192;
        const int c = col % 192;
        const int sel = c >> 6;
        const int d = c & 63;
        if (sel < 2) {
          // interleaved RoPE at position d (coalesced across lanes)
          const int p = d >> 1;
          const float sgn = (d & 1) ? 1.0f : -1.0f;
          const float qsc = (sel == 0) ? 0.18033688011112042592f : 1.0f;
          unsigned short* dst = (sel == 0) ? o0 : o1;
#pragma unroll
          for (int r = 0; r < 4; ++r) {
            const int row = m0 + wr * 64 + i * 16 + l4 * 4 + r;
            const int b = row >> 11, t = row & 2047;
            const float v = acc[i][j][r] + bv;
            const float vp = __shfl_xor(v, 1);
            const float cs = cosT[t * 32 + p];
            const float sn = sinT[t * 32 + p];
            const float res = (v * cs + sgn * vp * sn) * qsc;
            dst[((size_t)((b * CH + h) * CT + t)) * CDK + d] = f2bf(res);
          }
        } else {
          // V^T: pack the 4 consecutive-t values into one 8B store
          const int t0g = m0 + wr * 64 + i * 16 + l4 * 4;
          const int b = t0g >> 11, t = t0g & 2047;
          ushort4 pk;
          pk.x = f2bf(acc[i][j][0] + bv);
          pk.y = f2bf(acc[i][j][1] + bv);
          pk.z = f2bf(acc[i][j][2] + bv);
          pk.w = f2bf(acc[i][j][3] + bv);
          *(ushort4*)(&o2[((size_t)((b * CH + h) * CDK + d)) * CT + t]) = pk;
        }
      }
  }
}

// ---------------- flash attention v6: 4-buffer, ONE barrier per tile ----------
// 8 waves x 32 q-rows, 512 blocks (XCD-local + LPT remap). Buffer of tile t is
// t&3; stage(j+2) at iter j targets (j+2)&3 which barrier#1(j) has made safe
// (all waves finished buf (j-1)&3 == (j+3)&3 reads one iter earlier). Counted
// vmcnt unchanged. Max-free softmax, T12 P-frags, setprio.
__global__ __launch_bounds__(512, 4) void attn_fwd6(
    const unsigned short* __restrict__ qg, const unsigned short* __restrict__ kg,
    const unsigned short* __restrict__ vtg, unsigned short* __restrict__ ctx) {
  __shared__ __align__(16) unsigned short smem[32768];  // 64KB
  unsigned short* Ks = smem;             // 4 bufs x 4096 shorts
  unsigned short* Vt = smem + 16384;     // 4 bufs x 4096 shorts
  const int tid = threadIdx.x, lane = tid & 63, w = tid >> 6;
  const int l31 = lane & 31, hi = lane >> 5;
  const int b1 = blockIdx.x;
  const int g8 = b1 & 7, idx8 = b1 >> 3;
  const int qb = 7 - (idx8 & 7);
  const int bh = g8 + 8 * (idx8 >> 3);
  const unsigned short* qp = qg + ((size_t)bh * CT + qb * 256) * CDK;
  const unsigned short* kp = kg + (size_t)bh * CT * CDK;
  const unsigned short* vp = vtg + (size_t)bh * CDK * CT;

  bf16x8 qf[4];
  {
    const unsigned short* qrow = qp + (size_t)(w * 32 + l31) * CDK + hi * 8;
#pragma unroll
    for (int ks = 0; ks < 4; ++ks) qf[ks] = *(const bf16x8*)(qrow + ks * 16);
  }
#pragma unroll
  for (int ks = 0; ks < 4; ++ks)
    asm volatile("" :: "v"(*(const f32x4*)&qf[ks]));

  const int lr = lane >> 3;
  const int srow = w * 8 + lr;
  const int gsw = ((lane & 7) ^ lr) * 8;
  const unsigned short* ksrc = kp + (size_t)srow * CDK + gsw;
  const unsigned short* vsrc = vp + (size_t)srow * CT + gsw;
  const int ldo = w * 512;

  const int NJ = 4 * qb + 4;
  const int njw = ((qb * 256 + w * 32 + 31) >> 6) + 1;
  const int qrow_g = qb * 256 + w * 32 + l31;

  auto STAGE = [&](int t) {
    const int buf = t & 3;
    GLOAD_LDS16(ksrc + (size_t)t * 64 * CDK, Ks + buf * 4096 + ldo);
    GLOAD_LDS16(vsrc + (size_t)t * 64, Vt + buf * 4096 + ldo);
  };

  f32x16 oacc[2];
#pragma unroll
  for (int nb = 0; nb < 2; ++nb)
#pragma unroll
    for (int r = 0; r < 16; ++r) oacc[nb][r] = 0.f;
  float lsum = 0.f;

  STAGE(0);
  STAGE(1);

  for (int j = 0; j < NJ; ++j) {
    if (j + 2 < NJ) STAGE(j + 2);
    const int pend = NJ - 1 - j;
    if (pend >= 2)      asm volatile("s_waitcnt vmcnt(4)" ::: "memory");
    else if (pend == 1) asm volatile("s_waitcnt vmcnt(2)" ::: "memory");
    else                asm volatile("s_waitcnt vmcnt(0)" ::: "memory");
    __builtin_amdgcn_s_barrier();  // all waves' tile-j loads are in LDS

    if (j < njw) {
      const unsigned short* KB = Ks + (j & 3) * 4096;
      const unsigned short* VB = Vt + (j & 3) * 4096;

      f32x16 pacc[2];
      __builtin_amdgcn_s_setprio(1);
#pragma unroll
      for (int kb = 0; kb < 2; ++kb) {
#pragma unroll
        for (int r = 0; r < 16; ++r) pacc[kb][r] = 0.f;
#pragma unroll
        for (int ks = 0; ks < 4; ++ks) {
          const int row = kb * 32 + l31;
          bf16x8 kf = *(const bf16x8*)(KB + row * 64 + (((ks * 2 + hi) ^ (row & 7)) * 8));
          pacc[kb] = mfma32(kf, qf[ks], pacc[kb]);
        }
      }
      __builtin_amdgcn_s_setprio(0);

      if (j == njw - 1) {
        const int key0 = j * 64;
#pragma unroll
        for (int kb = 0; kb < 2; ++kb)
#pragma unroll
          for (int r = 0; r < 16; ++r) {
            const int key = key0 + kb * 32 + (r & 3) + 8 * (r >> 2) + 4 * hi;
            if (key > qrow_g) pacc[kb][r] = -1e30f;
          }
      }

#pragma unroll
      for (int kb = 0; kb < 2; ++kb)
#pragma unroll
        for (int r = 0; r < 16; ++r)
          pacc[kb][r] = __builtin_amdgcn_exp2f(pacc[kb][r]);
      float rs;
      {
        float t[16];
#pragma unroll
        for (int r = 0; r < 16; ++r) t[r] = pacc[0][r] + pacc[1][r];
#pragma unroll
        for (int s = 8; s > 0; s >>= 1)
#pragma unroll
          for (int r = 0; r < s; ++r) t[r] += t[r + s];
        rs = t[0];
      }
      {
        unsigned ru = __float_as_uint(rs);
        u32x2 sw = __builtin_amdgcn_permlane32_swap(ru, ru, false, false);
        rs += __uint_as_float(hi ? sw[0] : sw[1]);
      }
      lsum += rs;

      bf16x8 pf[4];
#pragma unroll
      for (int kb = 0; kb < 2; ++kb)
#pragma unroll
        for (int half = 0; half < 2; ++half) {
          const int b0i = half * 8;
          unsigned c0 = cvtpk(pacc[kb][b0i + 0], pacc[kb][b0i + 1]);
          unsigned c1 = cvtpk(pacc[kb][b0i + 2], pacc[kb][b0i + 3]);
          unsigned c2 = cvtpk(pacc[kb][b0i + 4], pacc[kb][b0i + 5]);
          unsigned c3 = cvtpk(pacc[kb][b0i + 6], pacc[kb][b0i + 7]);
          u32x2 r02 = __builtin_amdgcn_permlane32_swap(c0, c2, false, false);
          u32x2 r13 = __builtin_amdgcn_permlane32_swap(c1, c3, false, false);
          union { unsigned u[4]; bf16x8 v; } fr;
          fr.u[0] = r02[0]; fr.u[1] = r13[0]; fr.u[2] = r02[1]; fr.u[3] = r13[1];
          pf[kb * 2 + half] = fr.v;
        }

      __builtin_amdgcn_s_setprio(1);
#pragma unroll
      for (int nb = 0; nb < 2; ++nb)
#pragma unroll
        for (int ks = 0; ks < 4; ++ks) {
          const int row = nb * 32 + l31;
          bf16x8 vf = *(const bf16x8*)(VB + row * 64 + (((ks * 2 + hi) ^ (row & 7)) * 8));
          oacc[nb] = mfma32(vf, pf[ks], oacc[nb]);
        }
      __builtin_amdgcn_s_setprio(0);
    }
  }

  __syncthreads();  // drain before reusing smem as epilogue scratch

  unsigned short* tr = smem + w * 2048;
  const float inv = 1.f / lsum;
#pragma unroll
  for (int nb = 0; nb < 2; ++nb)
#pragma unroll
    for (int rp = 0; rp < 8; ++rp) {
      const int r = rp * 2;
      unsigned pkd = cvtpk(oacc[nb][r] * inv, oacc[nb][r + 1] * inv);
      const int d = nb * 32 + (r & 3) + 8 * (r >> 2) + 4 * hi;
      const int g = (d >> 3) ^ (l31 & 7);
      *(unsigned*)(tr + l31 * 64 + g * 8 + (d & 7)) = pkd;
    }
  const int b = bh >> 4, h = bh & 15;
#pragma unroll
  for (int s = 0; s < 4; ++s) {
    const int c = s * 64 + lane;
    const int qr = c >> 3, g = c & 7;
    s16x8 row = *(const s16x8*)(tr + qr * 64 + ((g ^ (qr & 7))) * 8);
    const int tok = qb * 256 + w * 32 + qr;
    *(s16x8*)(ctx + ((size_t)(b * CT + tok)) * CD + h * CDK + g * 8) = row;
  }
}

extern "C" void kernel_launch(void* const* d_in, const int* in_sizes, int n_in,
                              void* d_out, int out_size, void* d_ws, size_t ws_size,
                              hipStream_t stream) {
  (void)in_sizes; (void)n_in; (void)out_size; (void)ws_size;
  const float* x     = (const float*)d_in[0];
  const float* W_qkv = (const float*)d_in[1];
  const float* b_qkv = (const float*)d_in[2];
  const float* W_out = (const float*)d_in[3];
  const float* b_out = (const float*)d_in[4];
  const float* cosT  = (const float*)d_in[5];
  const float* sinT  = (const float*)d_in[6];
  float* out = (float*)d_out;

  unsigned short* xb   = (unsigned short*)d_ws;            // [8192][1024]
  unsigned short* wqt  = xb + (size_t)CBT * CD;            // [3072][1024]
  unsigned short* wot  = wqt + (size_t)3 * CD * CD;        // [1024][1024]
  unsigned short* qbuf = wot + (size_t)CD * CD;            // [64][2048][64]
  unsigned short* kbuf = qbuf + (size_t)CBH * CT * CDK;    // [64][2048][64]
  unsigned short* vbuf = kbuf + (size_t)CBH * CT * CDK;    // [64][64][2048] (V^T)
  unsigned short* ctx  = vbuf + (size_t)CBH * CT * CDK;    // [8192][1024]

  prep_inputs<<<dim3(8192 + 4096), 256, 0, stream>>>(x, xb, W_qkv, wqt,
                                                     W_out, wot);
  gemm_bt<0><<<dim3(CBT / 128, 3 * CD / 128), 256, 0, stream>>>(
      xb, wqt, b_qkv, qbuf, kbuf, vbuf, nullptr, cosT, sinT, CBT, 3 * CD, CD);
  attn_fwd6<<<dim3(512), 512, 0, stream>>>(qbuf, kbuf, vbuf, ctx);
  gemm_bt<1><<<dim3(CBT / 128, CD / 128), 256, 0, stream>>>(
      ctx, wot, b_out, nullptr, nullptr, nullptr, out, nullptr, nullptr,
      CBT, CD, CD);
}

// Round 18
// 161.347 us; speedup vs baseline: 1.1685x; 1.0002x over previous
//
#include <hip/hip_runtime.h>
#include <cmath>

typedef __attribute__((ext_vector_type(4))) float f32x4;
typedef __attribute__((ext_vector_type(16))) float f32x16;
typedef __attribute__((ext_vector_type(8))) __bf16 bf16x8;
typedef __attribute__((ext_vector_type(8))) short s16x8;
typedef __attribute__((ext_vector_type(2))) unsigned int u32x2;

#define CB 4
#define CT 2048
#define CD 1024
#define CH 16
#define CDK 64
#define CBT 8192   // B*T
#define CBH 64     // B*H

#define GLOAD_LDS16(g, l)                                              \
  __builtin_amdgcn_global_load_lds(                                    \
      (const __attribute__((address_space(1))) unsigned int*)(g),      \
      (__attribute__((address_space(3))) unsigned int*)(l), 16, 0, 0)

__device__ __forceinline__ unsigned short f2bf(float f) {
  union { float f; unsigned u; } x; x.f = f;
  unsigned r = x.u + 0x7fffu + ((x.u >> 16) & 1u);
  return (unsigned short)(r >> 16);
}
__device__ __forceinline__ float bf2f(unsigned short b) {
  union { unsigned u; float f; } x; x.u = ((unsigned)b) << 16;
  return x.f;
}
__device__ __forceinline__ f32x4 mfma16(bf16x8 a, bf16x8 b, f32x4 c) {
  return __builtin_amdgcn_mfma_f32_16x16x32_bf16(a, b, c, 0, 0, 0);
}
__device__ __forceinline__ f32x16 mfma32(bf16x8 a, bf16x8 b, f32x16 c) {
  return __builtin_amdgcn_mfma_f32_32x32x16_bf16(a, b, c, 0, 0, 0);
}
__device__ __forceinline__ unsigned cvtpk(float lo, float hi) {
  unsigned r;
  asm("v_cvt_pk_bf16_f32 %0, %1, %2" : "=v"(r) : "v"(lo), "v"(hi));
  return r;
}

// ---------------- merged prep: convert x (blocks 0..8191) + transpose weights ----------------
__global__ void prep_inputs(const float* __restrict__ x,
                            unsigned short* __restrict__ xb,
                            const float* __restrict__ wqkv,
                            unsigned short* __restrict__ wqt,
                            const float* __restrict__ wout,
                            unsigned short* __restrict__ wot) {
  __shared__ float tile[32][33];
  const int b = blockIdx.x, tid = threadIdx.x;
  if (b < 8192) {
    const int i = (b * 256 + tid) * 4;
    float4 v = *(const float4*)(x + i);
    ushort4 o;
    o.x = f2bf(v.x); o.y = f2bf(v.y); o.z = f2bf(v.z); o.w = f2bf(v.w);
    *(ushort4*)(xb + i) = o;
    return;
  }
  const int bt = b - 8192;
  const int bx = bt & 127, rt = bt >> 7;
  const int xx = tid & 31, y0 = tid >> 5;  // (32, 8)
  const float* src;
  unsigned short* dst;
  int C, ct;
  if (bx < 96) { src = wqkv; dst = wqt; C = 3072; ct = bx; }
  else         { src = wout; dst = wot; C = 1024; ct = bx - 96; }
  const int R = 1024;
#pragma unroll
  for (int k = 0; k < 4; ++k) {
    int r = rt * 32 + y0 + k * 8;
    tile[y0 + k * 8][xx] = src[(size_t)r * C + ct * 32 + xx];
  }
  __syncthreads();
#pragma unroll
  for (int k = 0; k < 4; ++k) {
    int c = ct * 32 + y0 + k * 8;
    dst[(size_t)c * R + rt * 32 + xx] = f2bf(tile[xx][y0 + k * 8]);
  }
}

// ---------------- GEMM: C = A(bf16 [M][K]) * Bt(bf16 [N][K])^T + bias ----------------
template <int MODE>
__global__ __launch_bounds__(256, 4) void gemm_bt(
    const unsigned short* __restrict__ A, const unsigned short* __restrict__ Bt,
    const float* __restrict__ bias, unsigned short* __restrict__ o0,
    unsigned short* __restrict__ o1, unsigned short* __restrict__ o2,
    float* __restrict__ fout, const float* __restrict__ cosT,
    const float* __restrict__ sinT, int M, int N, int K) {
  __shared__ __align__(16) unsigned short As[128 * 64];
  __shared__ __align__(16) unsigned short Bs[128 * 64];
  const int tid = threadIdx.x;
  const int lane = tid & 63, wid = tid >> 6;
  const int wr = wid >> 1, wc = wid & 1;
  const int m0 = blockIdx.x * 128, n0 = blockIdx.y * 128;
  const int l15 = lane & 15, l4 = lane >> 4;
  const int rx = l15 & 7;

  f32x4 acc[4][4];
#pragma unroll
  for (int i = 0; i < 4; ++i)
#pragma unroll
    for (int j = 0; j < 4; ++j) acc[i][j] = (f32x4){0.f, 0.f, 0.f, 0.f};

  const int srow = tid >> 3;
  const int scol = ((tid & 7) ^ (srow & 7)) * 8;
  const unsigned short* ag = A + (size_t)(m0 + srow) * K + scol;
  const unsigned short* bg = Bt + (size_t)(n0 + srow) * K + scol;
  unsigned short* asd = As + wid * 512;
  unsigned short* bsd = Bs + wid * 512;

  for (int k0 = 0; k0 < K; k0 += 64) {
#pragma unroll
    for (int p = 0; p < 4; ++p) {
      GLOAD_LDS16(ag + (size_t)(p * 32) * K + k0, asd + p * 2048);
      GLOAD_LDS16(bg + (size_t)(p * 32) * K + k0, bsd + p * 2048);
    }
    __syncthreads();
#pragma unroll
    for (int kk = 0; kk < 2; ++kk) {
      const int gsw = ((kk * 4 + l4) ^ rx) * 8;
      bf16x8 af[4], bfr[4];
#pragma unroll
      for (int i = 0; i < 4; ++i)
        af[i] = *(const bf16x8*)(&As[(wr * 64 + i * 16 + l15) * 64 + gsw]);
#pragma unroll
      for (int j = 0; j < 4; ++j)
        bfr[j] = *(const bf16x8*)(&Bs[(wc * 64 + j * 16 + l15) * 64 + gsw]);
#pragma unroll
      for (int i = 0; i < 4; ++i)
#pragma unroll
        for (int j = 0; j < 4; ++j)
          acc[i][j] = mfma16(af[i], bfr[j], acc[i][j]);
    }
    __syncthreads();
  }

  if (MODE == 1) {
#pragma unroll
    for (int i = 0; i < 4; ++i)
#pragma unroll
      for (int j = 0; j < 4; ++j) {
        const int row0 = m0 + wr * 64 + i * 16 + l4 * 4;
        const int col = n0 + wc * 64 + j * 16 + l15;
        const float bv = bias[col];
#pragma unroll
        for (int r = 0; r < 4; ++r)
          fout[(size_t)(row0 + r) * N + col] = acc[i][j][r] + bv;
      }
  } else {
#pragma unroll
    for (int i = 0; i < 4; ++i)
#pragma unroll
      for (int j = 0; j < 4; ++j) {
        const int col = n0 + wc * 64 + j * 16 + l15;
        const float bv = bias[col];
        const int h = col / 192;
        const int c = col % 192;
        const int sel = c >> 6;
        const int d = c & 63;
        if (sel < 2) {
          const int p = d >> 1;
          const float sgn = (d & 1) ? 1.0f : -1.0f;
          const float qsc = (sel == 0) ? 0.18033688011112042592f : 1.0f;
          unsigned short* dst = (sel == 0) ? o0 : o1;
#pragma unroll
          for (int r = 0; r < 4; ++r) {
            const int row = m0 + wr * 64 + i * 16 + l4 * 4 + r;
            const int b = row >> 11, t = row & 2047;
            const float v = acc[i][j][r] + bv;
            const float vp = __shfl_xor(v, 1);
            const float cs = cosT[t * 32 + p];
            const float sn = sinT[t * 32 + p];
            const float res = (v * cs + sgn * vp * sn) * qsc;
            dst[((size_t)((b * CH + h) * CT + t)) * CDK + d] = f2bf(res);
          }
        } else {
          const int t0g = m0 + wr * 64 + i * 16 + l4 * 4;
          const int b = t0g >> 11, t = t0g & 2047;
          ushort4 pk;
          pk.x = f2bf(acc[i][j][0] + bv);
          pk.y = f2bf(acc[i][j][1] + bv);
          pk.z = f2bf(acc[i][j][2] + bv);
          pk.w = f2bf(acc[i][j][3] + bv);
          *(ushort4*)(&o2[((size_t)((b * CH + h) * CDK + d)) * CT + t]) = pk;
        }
      }
  }
}

// ---------------- flash attention v7: KV-split work items ----------------
// 768 items: per bh, 12 items LPT-ordered: qb3(16t), qb7c0/c1(16t), qb6c0/c1(14t),
// qb2(12t), qb5c0/c1(12t), qb4c0/c1(10t), qb1(8t), qb0(4t). Max-free softmax =>
// chunk partials (O, l) are pure sums; split chunks write f32 partials + lsum,
// combined by attn_reduce. 4-buffer one-barrier pipeline, counted vmcnt.
__global__ __launch_bounds__(512, 4) void attn_fwd7(
    const unsigned short* __restrict__ qg, const unsigned short* __restrict__ kg,
    const unsigned short* __restrict__ vtg, unsigned short* __restrict__ ctx,
    float* __restrict__ opart, float* __restrict__ lpart) {
  __shared__ __align__(16) unsigned short smem[32768];  // 64KB
  unsigned short* Ks = smem;             // 4 bufs x 4096 shorts
  unsigned short* Vt = smem + 16384;     // 4 bufs x 4096 shorts
  const int tid = threadIdx.x, lane = tid & 63, w = tid >> 6;
  const int l31 = lane & 31, hi = lane >> 5;
  // work-item decode: XCD slot + LPT table
  const int g8 = blockIdx.x & 7, r = blockIdx.x >> 3;  // r: 0..95
  const int bh = g8 + 8 * (r / 12);
  const int sub = r % 12;
  const int qb = (int)((0x014455266773ULL >> (sub * 4)) & 15);
  const int ch = (0x294 >> sub) & 1;
  const int split = (0x3DE >> sub) & 1;
  const int NJ = 4 * qb + 4;
  const int halfn = 2 * qb + 2;
  const int jbeg = ch * halfn;
  const int jend = split ? (jbeg + halfn) : NJ;

  const unsigned short* qp = qg + ((size_t)bh * CT + qb * 256) * CDK;
  const unsigned short* kp = kg + (size_t)bh * CT * CDK;
  const unsigned short* vp = vtg + (size_t)bh * CDK * CT;

  bf16x8 qf[4];
  {
    const unsigned short* qrow = qp + (size_t)(w * 32 + l31) * CDK + hi * 8;
#pragma unroll
    for (int ks = 0; ks < 4; ++ks) qf[ks] = *(const bf16x8*)(qrow + ks * 16);
  }
#pragma unroll
  for (int ks = 0; ks < 4; ++ks)
    asm volatile("" :: "v"(*(const f32x4*)&qf[ks]));

  const int lr = lane >> 3;
  const int srow = w * 8 + lr;
  const int gsw = ((lane & 7) ^ lr) * 8;
  const unsigned short* ksrc = kp + (size_t)srow * CDK + gsw;
  const unsigned short* vsrc = vp + (size_t)srow * CT + gsw;
  const int ldo = w * 512;

  const int njw = ((qb * 256 + w * 32 + 31) >> 6) + 1;
  const int qrow_g = qb * 256 + w * 32 + l31;

  auto STAGE = [&](int t) {
    const int buf = t & 3;
    GLOAD_LDS16(ksrc + (size_t)t * 64 * CDK, Ks + buf * 4096 + ldo);
    GLOAD_LDS16(vsrc + (size_t)t * 64, Vt + buf * 4096 + ldo);
  };

  f32x16 oacc[2];
#pragma unroll
  for (int nb = 0; nb < 2; ++nb)
#pragma unroll
    for (int r2 = 0; r2 < 16; ++r2) oacc[nb][r2] = 0.f;
  float lsum = 0.f;

  STAGE(jbeg);
  STAGE(jbeg + 1);

  for (int j = jbeg; j < jend; ++j) {
    if (j + 2 < jend) STAGE(j + 2);
    const int pend = jend - 1 - j;
    if (pend >= 2)      asm volatile("s_waitcnt vmcnt(4)" ::: "memory");
    else if (pend == 1) asm volatile("s_waitcnt vmcnt(2)" ::: "memory");
    else                asm volatile("s_waitcnt vmcnt(0)" ::: "memory");
    __builtin_amdgcn_s_barrier();

    if (j < njw) {
      const unsigned short* KB = Ks + (j & 3) * 4096;
      const unsigned short* VB = Vt + (j & 3) * 4096;

      f32x16 pacc[2];
      __builtin_amdgcn_s_setprio(1);
#pragma unroll
      for (int kb = 0; kb < 2; ++kb) {
#pragma unroll
        for (int r2 = 0; r2 < 16; ++r2) pacc[kb][r2] = 0.f;
#pragma unroll
        for (int ks = 0; ks < 4; ++ks) {
          const int row = kb * 32 + l31;
          bf16x8 kf = *(const bf16x8*)(KB + row * 64 + (((ks * 2 + hi) ^ (row & 7)) * 8));
          pacc[kb] = mfma32(kf, qf[ks], pacc[kb]);
        }
      }
      __builtin_amdgcn_s_setprio(0);

      if (j == njw - 1) {
        const int key0 = j * 64;
#pragma unroll
        for (int kb = 0; kb < 2; ++kb)
#pragma unroll
          for (int r2 = 0; r2 < 16; ++r2) {
            const int key = key0 + kb * 32 + (r2 & 3) + 8 * (r2 >> 2) + 4 * hi;
            if (key > qrow_g) pacc[kb][r2] = -1e30f;
          }
      }

#pragma unroll
      for (int kb = 0; kb < 2; ++kb)
#pragma unroll
        for (int r2 = 0; r2 < 16; ++r2)
          pacc[kb][r2] = __builtin_amdgcn_exp2f(pacc[kb][r2]);
      float rs;
      {
        float t[16];
#pragma unroll
        for (int r2 = 0; r2 < 16; ++r2) t[r2] = pacc[0][r2] + pacc[1][r2];
#pragma unroll
        for (int s = 8; s > 0; s >>= 1)
#pragma unroll
          for (int r2 = 0; r2 < s; ++r2) t[r2] += t[r2 + s];
        rs = t[0];
      }
      {
        unsigned ru = __float_as_uint(rs);
        u32x2 sw = __builtin_amdgcn_permlane32_swap(ru, ru, false, false);
        rs += __uint_as_float(hi ? sw[0] : sw[1]);
      }
      lsum += rs;

      bf16x8 pf[4];
#pragma unroll
      for (int kb = 0; kb < 2; ++kb)
#pragma unroll
        for (int half = 0; half < 2; ++half) {
          const int b0i = half * 8;
          unsigned c0 = cvtpk(pacc[kb][b0i + 0], pacc[kb][b0i + 1]);
          unsigned c1 = cvtpk(pacc[kb][b0i + 2], pacc[kb][b0i + 3]);
          unsigned c2 = cvtpk(pacc[kb][b0i + 4], pacc[kb][b0i + 5]);
          unsigned c3 = cvtpk(pacc[kb][b0i + 6], pacc[kb][b0i + 7]);
          u32x2 r02 = __builtin_amdgcn_permlane32_swap(c0, c2, false, false);
          u32x2 r13 = __builtin_amdgcn_permlane32_swap(c1, c3, false, false);
          union { unsigned u[4]; bf16x8 v; } fr;
          fr.u[0] = r02[0]; fr.u[1] = r13[0]; fr.u[2] = r02[1]; fr.u[3] = r13[1];
          pf[kb * 2 + half] = fr.v;
        }

      __builtin_amdgcn_s_setprio(1);
#pragma unroll
      for (int nb = 0; nb < 2; ++nb)
#pragma unroll
        for (int ks = 0; ks < 4; ++ks) {
          const int row = nb * 32 + l31;
          bf16x8 vf = *(const bf16x8*)(VB + row * 64 + (((ks * 2 + hi) ^ (row & 7)) * 8));
          oacc[nb] = mfma32(vf, pf[ks], oacc[nb]);
        }
      __builtin_amdgcn_s_setprio(0);
    }
  }

  __syncthreads();  // drain before reusing smem as epilogue scratch

  if (!split) {
    // direct ctx epilogue (bf16 LDS transpose)
    unsigned short* tr = smem + w * 2048;
    const float inv = 1.f / lsum;
#pragma unroll
    for (int nb = 0; nb < 2; ++nb)
#pragma unroll
      for (int rp = 0; rp < 8; ++rp) {
        const int r2 = rp * 2;
        unsigned pkd = cvtpk(oacc[nb][r2] * inv, oacc[nb][r2 + 1] * inv);
        const int d = nb * 32 + (r2 & 3) + 8 * (r2 >> 2) + 4 * hi;
        const int g = (d >> 3) ^ (l31 & 7);
        *(unsigned*)(tr + l31 * 64 + g * 8 + (d & 7)) = pkd;
      }
    const int b = bh >> 4, h = bh & 15;
#pragma unroll
    for (int s = 0; s < 4; ++s) {
      const int c = s * 64 + lane;
      const int qr = c >> 3, g = c & 7;
      s16x8 row = *(const s16x8*)(tr + qr * 64 + ((g ^ (qr & 7))) * 8);
      const int tok = qb * 256 + w * 32 + qr;
      *(s16x8*)(ctx + ((size_t)(b * CT + tok)) * CD + h * CDK + g * 8) = row;
    }
  } else {
    // f32 partial epilogue: wave-private f32 LDS transpose -> opart [tok][d]
    float* trw = (float*)smem + w * 2048;  // 8KB per wave
#pragma unroll
    for (int nb = 0; nb < 2; ++nb)
#pragma unroll
      for (int r2 = 0; r2 < 16; ++r2) {
        const int d = nb * 32 + (r2 & 3) + 8 * (r2 >> 2) + 4 * hi;
        trw[l31 * 64 + (((d >> 2) ^ (l31 & 15)) << 2) + (d & 3)] = oacc[nb][r2];
      }
    const int tokrel0 = qb * 256 + w * 32 - 1024;  // qb>=4 here
    const size_t pbase = (size_t)(ch * 65536 + bh * 1024 + tokrel0);
#pragma unroll
    for (int s = 0; s < 8; ++s) {
      const int idx = s * 64 + lane;  // 0..511: 32 rows x 16 granules(4 f32)
      const int row = idx >> 4, gq = idx & 15;
      f32x4 v = *(const f32x4*)(trw + row * 64 + (((gq ^ (row & 15)) << 2)));
      *(f32x4*)(opart + (pbase + row) * 64 + gq * 4) = v;
    }
    if (hi == 0) lpart[ch * 65536 + bh * 1024 + tokrel0 + l31] = lsum;
  }
}

// ---------------- combine chunk partials for tokens 1024..2047 ----------------
__global__ __launch_bounds__(256) void attn_reduce(
    const float* __restrict__ opart, const float* __restrict__ lpart,
    unsigned short* __restrict__ ctx) {
  const int gid = blockIdx.x * 256 + threadIdx.x;
  const int row = gid >> 4, dq = (gid & 15) << 2;   // row: bh*1024 + tokrel
  f32x4 a = *(const f32x4*)(opart + (size_t)row * 64 + dq);
  f32x4 b4 = *(const f32x4*)(opart + ((size_t)65536 + row) * 64 + dq);
  const float inv = 1.f / (lpart[row] + lpart[65536 + row]);
  ushort4 o;
  o.x = f2bf((a[0] + b4[0]) * inv);
  o.y = f2bf((a[1] + b4[1]) * inv);
  o.z = f2bf((a[2] + b4[2]) * inv);
  o.w = f2bf((a[3] + b4[3]) * inv);
  const int bh = row >> 10, tokrel = row & 1023;
  const int b = bh >> 4, h = bh & 15;
  *(ushort4*)(ctx + ((size_t)(b * CT + 1024 + tokrel)) * CD + h * CDK + dq) = o;
}

extern "C" void kernel_launch(void* const* d_in, const int* in_sizes, int n_in,
                              void* d_out, int out_size, void* d_ws, size_t ws_size,
                              hipStream_t stream) {
  (void)in_sizes; (void)n_in; (void)out_size; (void)ws_size;
  const float* x     = (const float*)d_in[0];
  const float* W_qkv = (const float*)d_in[1];
  const float* b_qkv = (const float*)d_in[2];
  const float* W_out = (const float*)d_in[3];
  const float* b_out = (const float*)d_in[4];
  const float* cosT  = (const float*)d_in[5];
  const float* sinT  = (const float*)d_in[6];
  float* out = (float*)d_out;

  unsigned short* xb   = (unsigned short*)d_ws;            // [8192][1024]
  unsigned short* wqt  = xb + (size_t)CBT * CD;            // [3072][1024]
  unsigned short* wot  = wqt + (size_t)3 * CD * CD;        // [1024][1024]
  unsigned short* qbuf = wot + (size_t)CD * CD;            // [64][2048][64]
  unsigned short* kbuf = qbuf + (size_t)CBH * CT * CDK;    // [64][2048][64]
  unsigned short* vbuf = kbuf + (size_t)CBH * CT * CDK;    // [64][64][2048] (V^T)
  unsigned short* ctx  = vbuf + (size_t)CBH * CT * CDK;    // [8192][1024]
  float* opart = (float*)(ctx + (size_t)CBT * CD);         // [2][65536][64] f32
  float* lpart = opart + (size_t)2 * 65536 * 64;           // [2][65536] f32

  prep_inputs<<<dim3(8192 + 4096), 256, 0, stream>>>(x, xb, W_qkv, wqt,
                                                     W_out, wot);
  gemm_bt<0><<<dim3(CBT / 128, 3 * CD / 128), 256, 0, stream>>>(
      xb, wqt, b_qkv, qbuf, kbuf, vbuf, nullptr, cosT, sinT, CBT, 3 * CD, CD);
  attn_fwd7<<<dim3(768), 512, 0, stream>>>(qbuf, kbuf, vbuf, ctx, opart, lpart);
  attn_reduce<<<dim3(4096), 256, 0, stream>>>(opart, lpart, ctx);
  gemm_bt<1><<<dim3(CBT / 128, CD / 128), 256, 0, stream>>>(
      ctx, wot, b_out, nullptr, nullptr, nullptr, out, nullptr, nullptr,
      CBT, CD, CD);
}